// Round 2
// baseline (169.793 us; speedup 1.0000x reference)
//
#include <hip/hip_runtime.h>

// Shape-matching constraint projection, rot == Identity (see R0 analysis:
// the reference's SVD-derived rotation Vh^T @ Vh is identity up to SVD
// orthogonality noise; U and s are discarded).
//
//   com_c      = sum_p m*pred / sum_p m
//   delta_pos  = (V_w / V_compliance) * (init - (pred - com))
//   out[idx]   = V_predict[idx] + delta_pos
//   L_last     passes through.
//
// R1: 4 particles per thread (4 lanes per constraint) for 4x memory-level
// parallelism; int4 idx load, 3x float4 init load, 2-step shfl_xor reduction.
// L_last copy folded into trailing blocks of the same kernel (no extra
// dispatch).

__global__ __launch_bounds__(256) void shape_match_kernel(
    const float* __restrict__ V_predict,
    const float* __restrict__ L_last,
    const float* __restrict__ V_w,
    const float* __restrict__ V_mass,
    const int*   __restrict__ C_shape,
    const float* __restrict__ C_init,
    const float* __restrict__ V_comp,
    float*       __restrict__ out,
    float*       __restrict__ outL,
    int num_c, int work_blocks, int l_elems)
{
    if ((int)blockIdx.x >= work_blocks) {
        // ---- L_last passthrough (float4 copy) ----
        int i = (blockIdx.x - work_blocks) * blockDim.x + threadIdx.x;
        int n4 = l_elems >> 2;
        if (i < n4)
            reinterpret_cast<float4*>(outL)[i] =
                reinterpret_cast<const float4*>(L_last)[i];
        if (i == 0) {
            for (int r = n4 << 2; r < l_elems; ++r) outL[r] = L_last[r];
        }
        return;
    }

    const int t = blockIdx.x * blockDim.x + threadIdx.x;
    const int c = t >> 2;                 // 4 threads per constraint
    if (c >= num_c) return;
    const int gp0 = t << 2;               // first of this thread's 4 particle slots

    // 4 particle indices, one coalesced 16B load
    const int4 idx = *reinterpret_cast<const int4*>(C_shape + gp0);

    // init positions: 4 consecutive float3 = 48B contiguous, 16B-aligned
    const float4* ip = reinterpret_cast<const float4*>(C_init + (size_t)gp0 * 3);
    const float4 ia = ip[0];
    const float4 ib = ip[1];
    const float4 ic = ip[2];

    // independent gathers: 4 pred (12B) + 4 mass + 4 w + 4 comp
    const float3 p0 = *reinterpret_cast<const float3*>(V_predict + (size_t)idx.x * 3);
    const float3 p1 = *reinterpret_cast<const float3*>(V_predict + (size_t)idx.y * 3);
    const float3 p2 = *reinterpret_cast<const float3*>(V_predict + (size_t)idx.z * 3);
    const float3 p3 = *reinterpret_cast<const float3*>(V_predict + (size_t)idx.w * 3);

    const float m0 = V_mass[idx.x], m1 = V_mass[idx.y],
                m2 = V_mass[idx.z], m3 = V_mass[idx.w];
    const float w0 = V_w[idx.x], w1 = V_w[idx.y],
                w2 = V_w[idx.z], w3 = V_w[idx.w];
    const float k0 = V_comp[idx.x], k1 = V_comp[idx.y],
                k2 = V_comp[idx.z], k3 = V_comp[idx.w];

    // per-thread partial weighted sums over 4 particles
    float sx = m0 * p0.x + m1 * p1.x + m2 * p2.x + m3 * p3.x;
    float sy = m0 * p0.y + m1 * p1.y + m2 * p2.y + m3 * p3.y;
    float sz = m0 * p0.z + m1 * p1.z + m2 * p2.z + m3 * p3.z;
    float sm = m0 + m1 + m2 + m3;

    // 2-step butterfly across the 4-lane constraint group
    sx += __shfl_xor(sx, 1);
    sy += __shfl_xor(sy, 1);
    sz += __shfl_xor(sz, 1);
    sm += __shfl_xor(sm, 1);
    sx += __shfl_xor(sx, 2);
    sy += __shfl_xor(sy, 2);
    sz += __shfl_xor(sz, 2);
    sm += __shfl_xor(sm, 2);

    const float inv  = 1.0f / sm;
    const float comx = sx * inv;
    const float comy = sy * inv;
    const float comz = sz * inv;

    const float s0 = w0 / k0;
    const float s1 = w1 / k1;
    const float s2 = w2 / k2;
    const float s3 = w3 / k3;

    float3 o0, o1, o2, o3;
    o0.x = p0.x + s0 * (ia.x - p0.x + comx);
    o0.y = p0.y + s0 * (ia.y - p0.y + comy);
    o0.z = p0.z + s0 * (ia.z - p0.z + comz);

    o1.x = p1.x + s1 * (ia.w - p1.x + comx);
    o1.y = p1.y + s1 * (ib.x - p1.y + comy);
    o1.z = p1.z + s1 * (ib.y - p1.z + comz);

    o2.x = p2.x + s2 * (ib.z - p2.x + comx);
    o2.y = p2.y + s2 * (ib.w - p2.y + comy);
    o2.z = p2.z + s2 * (ic.x - p2.z + comz);

    o3.x = p3.x + s3 * (ic.y - p3.x + comx);
    o3.y = p3.y + s3 * (ic.z - p3.y + comy);
    o3.z = p3.z + s3 * (ic.w - p3.z + comz);

    *reinterpret_cast<float3*>(out + (size_t)idx.x * 3) = o0;
    *reinterpret_cast<float3*>(out + (size_t)idx.y * 3) = o1;
    *reinterpret_cast<float3*>(out + (size_t)idx.z * 3) = o2;
    *reinterpret_cast<float3*>(out + (size_t)idx.w * 3) = o3;
}

extern "C" void kernel_launch(void* const* d_in, const int* in_sizes, int n_in,
                              void* d_out, int out_size, void* d_ws, size_t ws_size,
                              hipStream_t stream)
{
    const float* V_predict = (const float*)d_in[0];
    const float* L_last    = (const float*)d_in[1];
    const float* V_w       = (const float*)d_in[2];
    const float* V_mass    = (const float*)d_in[3];
    const int*   C_shape   = (const int*)  d_in[4];
    const float* C_init    = (const float*)d_in[5];
    const float* V_comp    = (const float*)d_in[6];

    const int N     = in_sizes[0] / 3;   // vertices
    const int num_c = in_sizes[1];       // constraints (P fixed at 16)

    float* out  = (float*)d_out;
    float* outL = out + (size_t)N * 3;   // L_last output region

    const int block        = 256;
    const int work_threads = num_c * 4;                    // 4 particles/thread
    const int work_blocks  = (work_threads + block - 1) / block;
    const int n4           = (num_c + 3) / 4;              // float4 copy count
    const int l_blocks     = (n4 + block - 1) / block;

    shape_match_kernel<<<work_blocks + l_blocks, block, 0, stream>>>(
        V_predict, L_last, V_w, V_mass, C_shape, C_init, V_comp,
        out, outL, num_c, work_blocks, num_c);
}